// Round 12
// baseline (1809.936 us; speedup 1.0000x reference)
//
#include <hip/hip_runtime.h>
#include <math.h>

#define B_ 8
#define CIN_ 128
#define COUT_ 256
#define N_ 8192
#define M_ 2048
#define K_ 16

#define WORKERS 240          // non-FPS blocks in the mega kernel
#define NTILE 2048           // gemm: 8 b x 256 tiles (128n x 64o)
#define NGROUP 2048          // knn: 8 b x 256 groups of 8 rows

// ---------------------------------------------------------------------------
// DPP wave reductions (row_shr 1/2/4/8 + row_bcast 15/31): VALU-latency only.
// ---------------------------------------------------------------------------
__device__ __forceinline__ unsigned umax2(unsigned a, unsigned b) { return a > b ? a : b; }
__device__ __forceinline__ unsigned umin2(unsigned a, unsigned b) { return a < b ? a : b; }

__device__ __forceinline__ unsigned wave_reduce_umax(unsigned v) {
    v = umax2(v, (unsigned)__builtin_amdgcn_update_dpp(0, (int)v, 0x111, 0xf, 0xf, false));
    v = umax2(v, (unsigned)__builtin_amdgcn_update_dpp(0, (int)v, 0x112, 0xf, 0xf, false));
    v = umax2(v, (unsigned)__builtin_amdgcn_update_dpp(0, (int)v, 0x114, 0xf, 0xf, false));
    v = umax2(v, (unsigned)__builtin_amdgcn_update_dpp(0, (int)v, 0x118, 0xf, 0xf, false));
    v = umax2(v, (unsigned)__builtin_amdgcn_update_dpp(0, (int)v, 0x142, 0xf, 0xf, false));
    v = umax2(v, (unsigned)__builtin_amdgcn_update_dpp(0, (int)v, 0x143, 0xf, 0xf, false));
    return (unsigned)__builtin_amdgcn_readlane((int)v, 63);
}
__device__ __forceinline__ unsigned wave_reduce_umin(unsigned v) {
    v = umin2(v, (unsigned)__builtin_amdgcn_update_dpp(-1, (int)v, 0x111, 0xf, 0xf, false));
    v = umin2(v, (unsigned)__builtin_amdgcn_update_dpp(-1, (int)v, 0x112, 0xf, 0xf, false));
    v = umin2(v, (unsigned)__builtin_amdgcn_update_dpp(-1, (int)v, 0x114, 0xf, 0xf, false));
    v = umin2(v, (unsigned)__builtin_amdgcn_update_dpp(-1, (int)v, 0x118, 0xf, 0xf, false));
    v = umin2(v, (unsigned)__builtin_amdgcn_update_dpp(-1, (int)v, 0x142, 0xf, 0xf, false));
    v = umin2(v, (unsigned)__builtin_amdgcn_update_dpp(-1, (int)v, 0x143, 0xf, 0xf, false));
    return (unsigned)__builtin_amdgcn_readlane((int)v, 63);
}

// ---------------------------------------------------------------------------
// MEGA kernel — R10 structure (per-iter publication RESTORED after R11's
// batched variant regressed +48us) + two deltas:
//   * consumer spin backoff s_sleep(2)->s_sleep(16): ~8x fewer polls on the
//     producer's wflag cache lines (cross-XCD coherence contention is the
//     suspected publication tax mechanism; R11 showed producer-side batching
//     is not the knob). Frontier lag +<=0.5us/group vs 8us/group work.
//   * finalize FOLDED in: after worker barrier #2, block 0 computes
//     scale/bias (IDENTICAL summation order), threadfence+syncthreads, then
//     release-stores gbar[2]; all workers acquire-spin and apply
//     y = relu(s*y+t) in place (float4, rows grid-strided). Transitive
//     release/acquire chain makes all ymax + scale/bias stores visible.
//     s<0 keeps the gather fallback (gamma=1 -> never taken in practice).
// FPS decision math / knn / GEMM / BN order all FROZEN (R10-verified).
// ---------------------------------------------------------------------------
__global__ __launch_bounds__(512) void mega_kernel(const float* __restrict__ coords,
                                                   const float* __restrict__ x,
                                                   const float* __restrict__ W,
                                                   unsigned* __restrict__ wflag,
                                                   float* __restrict__ out_fps,
                                                   float* __restrict__ hp,
                                                   int* __restrict__ knn,
                                                   double* __restrict__ partial,
                                                   int* __restrict__ gbar,
                                                   float* __restrict__ ymax,
                                                   const float* __restrict__ gamma,
                                                   const float* __restrict__ beta,
                                                   float* __restrict__ scale,
                                                   float* __restrict__ bias) {
    __shared__ union {
        struct {
            float4 pts[N_];                      // 128 KiB
            unsigned long long kbuf[2][8];
            int wlist[M_];                       // 8 KiB
        } f;
        struct {
            float Xs[64][128];                   // 32 KiB
            float Wt[64][68];                    // 17 KiB
        } g;
        struct {
            float4 tile[1024];                   // 16 KiB
            double wacc[8][512];                 // 32 KiB (per-wave partials)
        } k;
    } sm;

    const int tid = threadIdx.x;
    const int lane = tid & 63;
    const int w = tid >> 6;                      // wave id 0..7

    if (blockIdx.x < B_) {
        // ================= FPS (R1/v4 exact + per-iter publication) ========
#pragma clang fp contract(off)
        const int b = blockIdx.x;
        const float* cb = coords + (size_t)b * 3 * N_;
        float4* pts = sm.f.pts;
        unsigned long long (*kbuf)[8] = sm.f.kbuf;
        int* wlist = sm.f.wlist;

        float px[16], py[16], pz[16], mind[16];
#pragma unroll
        for (int s = 0; s < 16; ++s) {
            int p = tid + s * 512;
            px[s] = cb[p];
            py[s] = cb[N_ + p];
            pz[s] = cb[2 * N_ + p];
            mind[s] = 1e10f;
            pts[p] = make_float4(px[s], py[s], pz[s], 0.f);
        }
        if (tid == 0)
            __hip_atomic_store(&wflag[(size_t)b * M_], 0u,
                               __ATOMIC_RELAXED, __HIP_MEMORY_SCOPE_AGENT);
        __syncthreads();
        float4 p0 = pts[0];
        float lx = p0.x, ly = p0.y, lz = p0.z;

        int par = 0;
        for (int m = 1; m < M_; ++m) {
            float bv = -1.0f; int bs = 0;
#pragma unroll
            for (int s = 0; s < 16; ++s) {
                float dx = px[s] - lx;
                float dy = py[s] - ly;
                float dz = pz[s] - lz;
                float d = __builtin_fmaf(dz, dz, __builtin_fmaf(dy, dy, dx * dx));  // frozen
                float mn = fminf(mind[s], d);
                mind[s] = mn;
                if (mn > bv) { bv = mn; bs = s; }   // strict >, ascending s: min idx in thread
            }
            int bi = tid + bs * 512;
            unsigned kd = __float_as_uint(bv);
            unsigned md = wave_reduce_umax(kd);
            unsigned cand = (kd == md) ? (unsigned)bi : 0xffffffffu;
            unsigned mi = wave_reduce_umin(cand);
            if (lane == 0)
                kbuf[par][w] = ((unsigned long long)md << 32) |
                               (unsigned long long)(0xffffffffu - mi);   // u64 max == lex rule
            __syncthreads();
            // vectorized tree max over 8 wave keys (exact; keys distinct across waves)
            const unsigned long long* kb = kbuf[par];
            ulonglong2 q0 = *(const ulonglong2*)&kb[0];
            ulonglong2 q1 = *(const ulonglong2*)&kb[2];
            ulonglong2 q2 = *(const ulonglong2*)&kb[4];
            ulonglong2 q3 = *(const ulonglong2*)&kb[6];
            unsigned long long a0 = q0.x > q0.y ? q0.x : q0.y;
            unsigned long long a1 = q1.x > q1.y ? q1.x : q1.y;
            unsigned long long a2 = q2.x > q2.y ? q2.x : q2.y;
            unsigned long long a3 = q3.x > q3.y ? q3.x : q3.y;
            unsigned long long b01 = a0 > a1 ? a0 : a1;
            unsigned long long b23 = a2 > a3 ? a2 : a3;
            unsigned long long best = b01 > b23 ? b01 : b23;
            int widx = (int)(0xffffffffu - (unsigned)(best & 0xffffffffull));
            widx = ((unsigned)widx < (unsigned)N_) ? widx : 0;             // fault guard
            float4 wp = pts[widx];                                         // LDS broadcast
            lx = wp.x; ly = wp.y; lz = wp.z;
            if (tid == 0) {
                wlist[m] = widx;
                __hip_atomic_store(&wflag[(size_t)b * M_ + m], (unsigned)widx,
                                   __ATOMIC_RELAXED, __HIP_MEMORY_SCOPE_AGENT);
            }
            par ^= 1;
        }

        // epilogue: out_fps only
        __syncthreads();
        for (int mm = tid; mm < M_; mm += 512) {
            int wi = (mm == 0) ? 0 : wlist[mm];
            wi = ((unsigned)wi < (unsigned)N_) ? wi : 0;                   // fault guard
            float4 wp = pts[wi];
            out_fps[(size_t)b * 3 * M_ + 0 * M_ + mm] = wp.x;
            out_fps[(size_t)b * 3 * M_ + 1 * M_ + mm] = wp.y;
            out_fps[(size_t)b * 3 * M_ + 2 * M_ + mm] = wp.z;
        }
    } else {
        const int wkr = blockIdx.x - B_;          // 0..239

        // ================= GEMM: hp[b][n][o] = sum_c x[b][c][n]*W[o][c] ====
        float (*Xs)[128] = sm.g.Xs;
        float (*Wt)[68] = sm.g.Wt;
        for (int t = wkr; t < NTILE; t += WORKERS) {
            const int b = t >> 8;                 // 256 tiles per batch
            const int rem = t & 255;
            const int n0 = (rem >> 2) * 128;
            const int o0 = (rem & 3) * 64;
            const int tn = (tid & 31) * 4;        // 0..124
            const int to = (tid >> 5) * 4;        // 0..60
            const float* xg = x + (size_t)b * CIN_ * N_;

            float acc[4][4] = {};
            for (int kk = 0; kk < CIN_; kk += 64) {
#pragma unroll
                for (int i = 0; i < 16; ++i) {    // 8192 elems of Xs
                    int e = tid + 512 * i;
                    int r = e >> 7, q = e & 127;
                    Xs[r][q] = xg[(size_t)(kk + r) * N_ + n0 + q];
                }
#pragma unroll
                for (int i = 0; i < 8; ++i) {     // 4096 elems of Wt
                    int e = tid + 512 * i;
                    int r = e >> 6, q = e & 63;
                    Wt[q][r] = W[(size_t)(o0 + r) * CIN_ + kk + q];
                }
                __syncthreads();
#pragma unroll 8
                for (int c = 0; c < 64; ++c) {
                    float4 a = *(const float4*)&Xs[c][tn];
                    float4 bb = *(const float4*)&Wt[c][to];
                    float av[4] = {a.x, a.y, a.z, a.w};
                    float bv[4] = {bb.x, bb.y, bb.z, bb.w};
#pragma unroll
                    for (int j = 0; j < 4; ++j)
#pragma unroll
                        for (int l = 0; l < 4; ++l)
                            acc[j][l] += av[j] * bv[l];
                }
                __syncthreads();
            }
#pragma unroll
            for (int j = 0; j < 4; ++j) {
                float4 v = make_float4(acc[j][0], acc[j][1], acc[j][2], acc[j][3]);
                *(float4*)&hp[((size_t)b * N_ + n0 + tn + j) * COUT_ + o0 + to] = v;
            }
        }

        // ==== worker barrier #1 (all 240 co-resident; R9-verified pattern) ==
        __threadfence();
        if (tid == 0) {
            __hip_atomic_fetch_add(&gbar[0], 1, __ATOMIC_RELEASE, __HIP_MEMORY_SCOPE_AGENT);
            while (__hip_atomic_load(&gbar[0], __ATOMIC_ACQUIRE, __HIP_MEMORY_SCOPE_AGENT) < WORKERS)
                __builtin_amdgcn_s_sleep(8);
        }
        __syncthreads();

        // ======== kNN (progressive consumer) + BN stats + fused k-max ======
        {
#pragma clang fp contract(off)
            float4* tile = sm.k.tile;
            double sAcc[4] = {0.0, 0.0, 0.0, 0.0};
            double s2Acc[4] = {0.0, 0.0, 0.0, 0.0};

            for (int g = wkr; g < NGROUP; g += WORKERS) {
                const int b = g & 7;
                const int mg = g >> 3;
                const int m = mg * 8 + w;
                const int row = b * M_ + m;
                const float* cb = coords + (size_t)b * 3 * N_;

                unsigned widx;
                while ((widx = __hip_atomic_load(&wflag[row], __ATOMIC_RELAXED,
                                                 __HIP_MEMORY_SCOPE_AGENT)) == 0xffffffffu)
                    __builtin_amdgcn_s_sleep(16);   // longer backoff: fewer polls on
                                                    // the producer's wflag lines
                widx = (widx < (unsigned)N_) ? widx : 0;   // fault guard

                const float fx = cb[widx];
                const float fy = cb[N_ + widx];
                const float fz = cb[2 * N_ + widx];        // same floats as old fpts
                const float sf = __builtin_fmaf(fz, fz, __builtin_fmaf(fy, fy, fx * fx)); // frozen

                float ed = INFINITY; int ei = 0x7fffffff;  // distributed list entry
                float tau_d = INFINITY; int tau_i = 0x7fffffff;

                for (int t = 0; t < 8; ++t) {
                    const int base = t * 1024;
#pragma unroll
                    for (int j = 0; j < 2; ++j) {
                        int idx = tid + 512 * j;
                        int n = base + idx;
                        float gx = cb[n], gy = cb[N_ + n], gz = cb[2 * N_ + n];
                        float sp = __builtin_fmaf(gz, gz, __builtin_fmaf(gy, gy, gx * gx)); // frozen
                        tile[idx] = make_float4(gx, gy, gz, sp);
                    }
                    __syncthreads();
                    for (int s = 0; s < 16; ++s) {
                        int l = s * 64 + lane;
                        float4 p = tile[l];
                        int n = base + l;
                        float dot = __builtin_fmaf(fz, p.z, __builtin_fmaf(fy, p.y, fx * p.x)); // frozen
                        float d = (sf + p.w) - 2.0f * dot;                                      // frozen
                        bool q = (d < tau_d) || (d == tau_d && n < tau_i);
                        unsigned long long bal = __ballot(q);
                        while (bal) {
                            int lb = __ffsll(bal) - 1;
                            bal &= bal - 1;
                            float dv = __shfl(d, lb);
                            int   iv = __shfl(n, lb);
                            if ((dv < tau_d) || (dv == tau_d && iv < tau_i)) {
                                float pud = __shfl_up(ed, 1);
                                int   pui = __shfl_up(ei, 1);
                                bool cs = (dv < ed) || (dv == ed && iv < ei);
                                bool cp = (lane != 0) && ((dv < pud) || (dv == pud && iv < pui));
                                ed = cs ? (cp ? pud : dv) : ed;
                                ei = cs ? (cp ? pui : iv) : ei;
                                tau_d = __shfl(ed, 15);
                                tau_i = __shfl(ei, 15);
                            }
                        }
                    }
                    __syncthreads();
                }
                if (lane < K_) {
                    int v = ei;
                    v = ((unsigned)v < (unsigned)N_) ? v : 0;          // fault guard
                    knn[(size_t)row * K_ + lane] = v;
                }
                // BN stats + k-max over the SAME loads. lane L owns o = L+64j.
                float mx[4] = {-INFINITY, -INFINITY, -INFINITY, -INFINITY};
#pragma unroll
                for (int k = 0; k < K_; ++k) {
                    int iv = __shfl(ei, k);
                    iv = ((unsigned)iv < (unsigned)N_) ? iv : 0;       // fault guard
                    const float* hrow = hp + ((size_t)b * N_ + iv) * COUT_;
#pragma unroll
                    for (int j = 0; j < 4; ++j) {
                        float hv = hrow[lane + 64 * j];
                        double h = (double)hv;
                        sAcc[j] += h;
                        s2Acc[j] += h * h;
                        mx[j] = fmaxf(mx[j], hv);
                    }
                }
                // store k-max at its FINAL transposed y address (hidden scatter)
#pragma unroll
                for (int j = 0; j < 4; ++j)
                    ymax[((size_t)b * COUT_ + (lane + 64 * j)) * M_ + m] = mx[j];
            }

            // per-wave partials -> LDS, cross-wave reduce, block partial out
            double (*wacc)[512] = sm.k.wacc;
#pragma unroll
            for (int j = 0; j < 4; ++j) {
                wacc[w][lane + 64 * j] = sAcc[j];
                wacc[w][256 + lane + 64 * j] = s2Acc[j];
            }
            __syncthreads();
            double tsum = 0.0;
#pragma unroll
            for (int wv = 0; wv < 8; ++wv) tsum += wacc[wv][tid];
            partial[(size_t)wkr * 512 + tid] = tsum;
        }

        // ==== worker barrier #2; block 0 computes scale/bias and releases ==
        __threadfence();
        if (tid == 0)
            __hip_atomic_fetch_add(&gbar[1], 1, __ATOMIC_RELEASE, __HIP_MEMORY_SCOPE_AGENT);
        if (wkr == 0) {
            if (tid == 0) {
                while (__hip_atomic_load(&gbar[1], __ATOMIC_ACQUIRE, __HIP_MEMORY_SCOPE_AGENT) < WORKERS)
                    __builtin_amdgcn_s_sleep(8);
            }
            __syncthreads();
            if (tid < 256) {
                int o = tid;
                double s = 0.0, s2 = 0.0;
                for (int j = 0; j < WORKERS; ++j) {          // IDENTICAL order to old bn_final
                    s += partial[(size_t)j * 512 + o];
                    s2 += partial[(size_t)j * 512 + 256 + o];
                }
                const double inv = 1.0 / (double)(B_ * M_ * K_);
                double mean = s * inv;
                double var = s2 * inv - mean * mean;
                if (var < 0.0) var = 0.0;
                double r = 1.0 / sqrt(var + 1e-5);
                double gm = (double)gamma[o];
                scale[o] = (float)(r * gm);
                bias[o] = (float)((double)beta[o] - mean * r * gm);
            }
            __threadfence();
            __syncthreads();
            if (tid == 0)
                __hip_atomic_store(&gbar[2], 1, __ATOMIC_RELEASE, __HIP_MEMORY_SCOPE_AGENT);
        }
        // all workers wait for scale/bias (transitive hb: every worker's
        // ymax/partial stores -> gbar[1] release -> block0 acquire -> compute
        // -> gbar[2] release -> this acquire)
        if (tid == 0) {
            while (__hip_atomic_load(&gbar[2], __ATOMIC_ACQUIRE, __HIP_MEMORY_SCOPE_AGENT) == 0)
                __builtin_amdgcn_s_sleep(8);
        }
        __syncthreads();

        // ==== fused finalize: y = relu(s*ymax+t) in place, rows (b,o) ======
        for (int r = wkr; r < B_ * COUT_; r += WORKERS) {
            const int o = r & 255;
            const float s = scale[o];
            const float t = bias[o];
            float* yrow = ymax + (size_t)r * M_;
            if (s >= 0.0f) {
                float4* y4 = (float4*)yrow;
                float4 v = y4[tid];               // 512 thr x float4 = 2048 = M
                v.x = fmaxf(v.x * s + t, 0.0f);   // same expression as old finalize
                v.y = fmaxf(v.y * s + t, 0.0f);
                v.z = fmaxf(v.z * s + t, 0.0f);
                v.w = fmaxf(v.w * s + t, 0.0f);
                y4[tid] = v;
            } else {
                const int b = r >> 8;
                for (int i = 0; i < 4; ++i) {
                    int m = tid * 4 + i;
                    float v = -INFINITY;
                    for (int k = 0; k < K_; ++k) {
                        int n = knn[(size_t)(b * M_ + m) * K_ + k];
                        n = ((unsigned)n < (unsigned)N_) ? n : 0;   // fault guard
                        float h = hp[((size_t)b * N_ + n) * COUT_ + o];
                        v = fmaxf(v, h * s + t);
                    }
                    yrow[m] = fmaxf(v, 0.0f);
                }
            }
        }
    }
}

__global__ void sentinel_kernel(float* out, float v) { out[0] = v; }

// ---------------------------------------------------------------------------
extern "C" void kernel_launch(void* const* d_in, const int* in_sizes, int n_in,
                              void* d_out, int out_size, void* d_ws, size_t ws_size,
                              hipStream_t stream) {
    const float* x = (const float*)d_in[0];
    const float* coords = (const float*)d_in[1];
    const float* W = (const float*)d_in[2];
    const float* gamma = (const float*)d_in[3];
    const float* beta = (const float*)d_in[4];
    float* y = (float*)d_out;
    float* out_fps = y + (size_t)B_ * COUT_ * M_;     // fps_coords after y (f32)

    if (n_in != 5 ||
        in_sizes[0] != B_ * CIN_ * N_ ||
        in_sizes[1] != B_ * 3 * N_ ||
        in_sizes[2] != COUT_ * CIN_ ||
        in_sizes[3] != COUT_ || in_sizes[4] != COUT_ ||
        out_size != B_ * COUT_ * M_ + B_ * 3 * M_) {
        sentinel_kernel<<<1, 1, 0, stream>>>(y, -2.0e6f);
        return;
    }

    const size_t HP_BYTES = (size_t)B_ * N_ * COUT_ * 4;          // 64 MB
    const size_t KNN_BYTES = (size_t)B_ * M_ * K_ * 4;            // 1 MB
    const size_t PART_BYTES = (size_t)WORKERS * 512 * 8;          // 983 KB
    const size_t WFLAG_BYTES = (size_t)B_ * M_ * 4;               // 64 KB
    const size_t NEED = HP_BYTES + KNN_BYTES + PART_BYTES + WFLAG_BYTES + 8192;
    if (ws_size < NEED) {
        sentinel_kernel<<<1, 1, 0, stream>>>(y, -1.0e6f);
        return;
    }
    char* ws = (char*)d_ws;
    float* hp = (float*)ws;
    int* knn = (int*)(ws + HP_BYTES);
    double* partial = (double*)(ws + HP_BYTES + KNN_BYTES);
    unsigned* wflag = (unsigned*)(ws + HP_BYTES + KNN_BYTES + PART_BYTES);
    char* tail = ws + HP_BYTES + KNN_BYTES + PART_BYTES + WFLAG_BYTES;
    int* gbar = (int*)tail;                                        // 3 counters
    float* scale = (float*)(tail + 256);
    float* bias = scale + 256;

    (void)hipMemsetAsync(wflag, 0xFF, WFLAG_BYTES, stream);        // winner flags = empty
    (void)hipMemsetAsync(gbar, 0, 256, stream);                    // all barriers = 0

    mega_kernel<<<B_ + WORKERS, 512, 0, stream>>>(coords, x, W, wflag, out_fps,
                                                  hp, knn, partial, gbar, y,
                                                  gamma, beta, scale, bias);
}

// Round 13
// 1664.809 us; speedup vs baseline: 1.0872x; 1.0872x over previous
//
#include <hip/hip_runtime.h>
#include <math.h>

#define B_ 8
#define CIN_ 128
#define COUT_ 256
#define N_ 8192
#define M_ 2048
#define K_ 16

#define WORKERS 240          // non-FPS blocks in the mega kernel
#define NTILE 2048           // gemm: 8 b x 256 tiles (128n x 64o)
#define NGROUP 2048          // knn: 8 b x 256 groups of 8 rows
#define FSTRIDE 16           // wflag stride in u32: one flag per 64B line

// ---------------------------------------------------------------------------
// DPP wave reductions (row_shr 1/2/4/8 + row_bcast 15/31): VALU-latency only.
// ---------------------------------------------------------------------------
__device__ __forceinline__ unsigned umax2(unsigned a, unsigned b) { return a > b ? a : b; }
__device__ __forceinline__ unsigned umin2(unsigned a, unsigned b) { return a < b ? a : b; }

__device__ __forceinline__ unsigned wave_reduce_umax(unsigned v) {
    v = umax2(v, (unsigned)__builtin_amdgcn_update_dpp(0, (int)v, 0x111, 0xf, 0xf, false));
    v = umax2(v, (unsigned)__builtin_amdgcn_update_dpp(0, (int)v, 0x112, 0xf, 0xf, false));
    v = umax2(v, (unsigned)__builtin_amdgcn_update_dpp(0, (int)v, 0x114, 0xf, 0xf, false));
    v = umax2(v, (unsigned)__builtin_amdgcn_update_dpp(0, (int)v, 0x118, 0xf, 0xf, false));
    v = umax2(v, (unsigned)__builtin_amdgcn_update_dpp(0, (int)v, 0x142, 0xf, 0xf, false));
    v = umax2(v, (unsigned)__builtin_amdgcn_update_dpp(0, (int)v, 0x143, 0xf, 0xf, false));
    return (unsigned)__builtin_amdgcn_readlane((int)v, 63);
}
__device__ __forceinline__ unsigned wave_reduce_umin(unsigned v) {
    v = umin2(v, (unsigned)__builtin_amdgcn_update_dpp(-1, (int)v, 0x111, 0xf, 0xf, false));
    v = umin2(v, (unsigned)__builtin_amdgcn_update_dpp(-1, (int)v, 0x112, 0xf, 0xf, false));
    v = umin2(v, (unsigned)__builtin_amdgcn_update_dpp(-1, (int)v, 0x114, 0xf, 0xf, false));
    v = umin2(v, (unsigned)__builtin_amdgcn_update_dpp(-1, (int)v, 0x118, 0xf, 0xf, false));
    v = umin2(v, (unsigned)__builtin_amdgcn_update_dpp(-1, (int)v, 0x142, 0xf, 0xf, false));
    v = umin2(v, (unsigned)__builtin_amdgcn_update_dpp(-1, (int)v, 0x143, 0xf, 0xf, false));
    return (unsigned)__builtin_amdgcn_readlane((int)v, 63);
}

// ---------------------------------------------------------------------------
// MEGA kernel — R10 structure VERBATIM (best measured: 1669us total) with ONE
// delta: wflag padded to one flag per 64B cache line (FSTRIDE=16 u32).
//   Mechanism under test: publication tax (~85us, R4 vs R7) = producer's
//   per-iter agent store fighting ~16 parked consumer waves whose polls all
//   cache the SAME 64B line (flags m..m+15). Padding makes each store's line
//   polled by exactly ONE wave -> cheaper exclusive-ownership acquisition.
//   R11 (producer batching) and R12 (sleep16 + finalize fold) both hurt;
//   this is the remaining single-variable test of the contention theory.
// FPS decision math / knn / GEMM / BN order / finalize all R10-FROZEN.
// ---------------------------------------------------------------------------
__global__ __launch_bounds__(512) void mega_kernel(const float* __restrict__ coords,
                                                   const float* __restrict__ x,
                                                   const float* __restrict__ W,
                                                   unsigned* __restrict__ wflag,
                                                   float* __restrict__ out_fps,
                                                   float* __restrict__ hp,
                                                   int* __restrict__ knn,
                                                   double* __restrict__ partial,
                                                   int* __restrict__ gbar,
                                                   float* __restrict__ ymax,
                                                   const float* __restrict__ gamma,
                                                   const float* __restrict__ beta,
                                                   float* __restrict__ scale,
                                                   float* __restrict__ bias) {
    __shared__ union {
        struct {
            float4 pts[N_];                      // 128 KiB
            unsigned long long kbuf[2][8];
            int wlist[M_];                       // 8 KiB
        } f;
        struct {
            float Xs[64][128];                   // 32 KiB
            float Wt[64][68];                    // 17 KiB
        } g;
        struct {
            float4 tile[1024];                   // 16 KiB
            double wacc[8][512];                 // 32 KiB (per-wave partials)
        } k;
    } sm;

    const int tid = threadIdx.x;
    const int lane = tid & 63;
    const int w = tid >> 6;                      // wave id 0..7

    if (blockIdx.x < B_) {
        // ================= FPS (R1/v4 exact + per-iter publication) ========
#pragma clang fp contract(off)
        const int b = blockIdx.x;
        const float* cb = coords + (size_t)b * 3 * N_;
        float4* pts = sm.f.pts;
        unsigned long long (*kbuf)[8] = sm.f.kbuf;
        int* wlist = sm.f.wlist;

        float px[16], py[16], pz[16], mind[16];
#pragma unroll
        for (int s = 0; s < 16; ++s) {
            int p = tid + s * 512;
            px[s] = cb[p];
            py[s] = cb[N_ + p];
            pz[s] = cb[2 * N_ + p];
            mind[s] = 1e10f;
            pts[p] = make_float4(px[s], py[s], pz[s], 0.f);
        }
        if (tid == 0)
            __hip_atomic_store(&wflag[(size_t)b * M_ * FSTRIDE], 0u,
                               __ATOMIC_RELAXED, __HIP_MEMORY_SCOPE_AGENT);
        __syncthreads();
        float4 p0 = pts[0];
        float lx = p0.x, ly = p0.y, lz = p0.z;

        int par = 0;
        for (int m = 1; m < M_; ++m) {
            float bv = -1.0f; int bs = 0;
#pragma unroll
            for (int s = 0; s < 16; ++s) {
                float dx = px[s] - lx;
                float dy = py[s] - ly;
                float dz = pz[s] - lz;
                float d = __builtin_fmaf(dz, dz, __builtin_fmaf(dy, dy, dx * dx));  // frozen
                float mn = fminf(mind[s], d);
                mind[s] = mn;
                if (mn > bv) { bv = mn; bs = s; }   // strict >, ascending s: min idx in thread
            }
            int bi = tid + bs * 512;
            unsigned kd = __float_as_uint(bv);
            unsigned md = wave_reduce_umax(kd);
            unsigned cand = (kd == md) ? (unsigned)bi : 0xffffffffu;
            unsigned mi = wave_reduce_umin(cand);
            if (lane == 0)
                kbuf[par][w] = ((unsigned long long)md << 32) |
                               (unsigned long long)(0xffffffffu - mi);   // u64 max == lex rule
            __syncthreads();
            // vectorized tree max over 8 wave keys (exact; keys distinct across waves)
            const unsigned long long* kb = kbuf[par];
            ulonglong2 q0 = *(const ulonglong2*)&kb[0];
            ulonglong2 q1 = *(const ulonglong2*)&kb[2];
            ulonglong2 q2 = *(const ulonglong2*)&kb[4];
            ulonglong2 q3 = *(const ulonglong2*)&kb[6];
            unsigned long long a0 = q0.x > q0.y ? q0.x : q0.y;
            unsigned long long a1 = q1.x > q1.y ? q1.x : q1.y;
            unsigned long long a2 = q2.x > q2.y ? q2.x : q2.y;
            unsigned long long a3 = q3.x > q3.y ? q3.x : q3.y;
            unsigned long long b01 = a0 > a1 ? a0 : a1;
            unsigned long long b23 = a2 > a3 ? a2 : a3;
            unsigned long long best = b01 > b23 ? b01 : b23;
            int widx = (int)(0xffffffffu - (unsigned)(best & 0xffffffffull));
            widx = ((unsigned)widx < (unsigned)N_) ? widx : 0;             // fault guard
            float4 wp = pts[widx];                                         // LDS broadcast
            lx = wp.x; ly = wp.y; lz = wp.z;
            if (tid == 0) {
                wlist[m] = widx;
                __hip_atomic_store(&wflag[((size_t)b * M_ + m) * FSTRIDE], (unsigned)widx,
                                   __ATOMIC_RELAXED, __HIP_MEMORY_SCOPE_AGENT);
            }
            par ^= 1;
        }

        // epilogue: out_fps only
        __syncthreads();
        for (int mm = tid; mm < M_; mm += 512) {
            int wi = (mm == 0) ? 0 : wlist[mm];
            wi = ((unsigned)wi < (unsigned)N_) ? wi : 0;                   // fault guard
            float4 wp = pts[wi];
            out_fps[(size_t)b * 3 * M_ + 0 * M_ + mm] = wp.x;
            out_fps[(size_t)b * 3 * M_ + 1 * M_ + mm] = wp.y;
            out_fps[(size_t)b * 3 * M_ + 2 * M_ + mm] = wp.z;
        }
    } else {
        const int wkr = blockIdx.x - B_;          // 0..239

        // ================= GEMM: hp[b][n][o] = sum_c x[b][c][n]*W[o][c] ====
        float (*Xs)[128] = sm.g.Xs;
        float (*Wt)[68] = sm.g.Wt;
        for (int t = wkr; t < NTILE; t += WORKERS) {
            const int b = t >> 8;                 // 256 tiles per batch
            const int rem = t & 255;
            const int n0 = (rem >> 2) * 128;
            const int o0 = (rem & 3) * 64;
            const int tn = (tid & 31) * 4;        // 0..124
            const int to = (tid >> 5) * 4;        // 0..60
            const float* xg = x + (size_t)b * CIN_ * N_;

            float acc[4][4] = {};
            for (int kk = 0; kk < CIN_; kk += 64) {
#pragma unroll
                for (int i = 0; i < 16; ++i) {    // 8192 elems of Xs
                    int e = tid + 512 * i;
                    int r = e >> 7, q = e & 127;
                    Xs[r][q] = xg[(size_t)(kk + r) * N_ + n0 + q];
                }
#pragma unroll
                for (int i = 0; i < 8; ++i) {     // 4096 elems of Wt
                    int e = tid + 512 * i;
                    int r = e >> 6, q = e & 63;
                    Wt[q][r] = W[(size_t)(o0 + r) * CIN_ + kk + q];
                }
                __syncthreads();
#pragma unroll 8
                for (int c = 0; c < 64; ++c) {
                    float4 a = *(const float4*)&Xs[c][tn];
                    float4 bb = *(const float4*)&Wt[c][to];
                    float av[4] = {a.x, a.y, a.z, a.w};
                    float bv[4] = {bb.x, bb.y, bb.z, bb.w};
#pragma unroll
                    for (int j = 0; j < 4; ++j)
#pragma unroll
                        for (int l = 0; l < 4; ++l)
                            acc[j][l] += av[j] * bv[l];
                }
                __syncthreads();
            }
#pragma unroll
            for (int j = 0; j < 4; ++j) {
                float4 v = make_float4(acc[j][0], acc[j][1], acc[j][2], acc[j][3]);
                *(float4*)&hp[((size_t)b * N_ + n0 + tn + j) * COUT_ + o0 + to] = v;
            }
        }

        // ==== worker barrier #1 (all 240 co-resident; R9-verified pattern) ==
        __threadfence();
        if (tid == 0) {
            __hip_atomic_fetch_add(&gbar[0], 1, __ATOMIC_RELEASE, __HIP_MEMORY_SCOPE_AGENT);
            while (__hip_atomic_load(&gbar[0], __ATOMIC_ACQUIRE, __HIP_MEMORY_SCOPE_AGENT) < WORKERS)
                __builtin_amdgcn_s_sleep(8);
        }
        __syncthreads();

        // ======== kNN (progressive consumer) + BN stats + fused k-max ======
        {
#pragma clang fp contract(off)
            float4* tile = sm.k.tile;
            double sAcc[4] = {0.0, 0.0, 0.0, 0.0};
            double s2Acc[4] = {0.0, 0.0, 0.0, 0.0};

            for (int g = wkr; g < NGROUP; g += WORKERS) {
                const int b = g & 7;
                const int mg = g >> 3;
                const int m = mg * 8 + w;
                const int row = b * M_ + m;
                const float* cb = coords + (size_t)b * 3 * N_;

                unsigned widx;
                while ((widx = __hip_atomic_load(&wflag[(size_t)row * FSTRIDE],
                                                 __ATOMIC_RELAXED,
                                                 __HIP_MEMORY_SCOPE_AGENT)) == 0xffffffffu)
                    __builtin_amdgcn_s_sleep(2);
                widx = (widx < (unsigned)N_) ? widx : 0;   // fault guard

                const float fx = cb[widx];
                const float fy = cb[N_ + widx];
                const float fz = cb[2 * N_ + widx];        // same floats as old fpts
                const float sf = __builtin_fmaf(fz, fz, __builtin_fmaf(fy, fy, fx * fx)); // frozen

                float ed = INFINITY; int ei = 0x7fffffff;  // distributed list entry
                float tau_d = INFINITY; int tau_i = 0x7fffffff;

                for (int t = 0; t < 8; ++t) {
                    const int base = t * 1024;
#pragma unroll
                    for (int j = 0; j < 2; ++j) {
                        int idx = tid + 512 * j;
                        int n = base + idx;
                        float gx = cb[n], gy = cb[N_ + n], gz = cb[2 * N_ + n];
                        float sp = __builtin_fmaf(gz, gz, __builtin_fmaf(gy, gy, gx * gx)); // frozen
                        tile[idx] = make_float4(gx, gy, gz, sp);
                    }
                    __syncthreads();
                    for (int s = 0; s < 16; ++s) {
                        int l = s * 64 + lane;
                        float4 p = tile[l];
                        int n = base + l;
                        float dot = __builtin_fmaf(fz, p.z, __builtin_fmaf(fy, p.y, fx * p.x)); // frozen
                        float d = (sf + p.w) - 2.0f * dot;                                      // frozen
                        bool q = (d < tau_d) || (d == tau_d && n < tau_i);
                        unsigned long long bal = __ballot(q);
                        while (bal) {
                            int lb = __ffsll(bal) - 1;
                            bal &= bal - 1;
                            float dv = __shfl(d, lb);
                            int   iv = __shfl(n, lb);
                            if ((dv < tau_d) || (dv == tau_d && iv < tau_i)) {
                                float pud = __shfl_up(ed, 1);
                                int   pui = __shfl_up(ei, 1);
                                bool cs = (dv < ed) || (dv == ed && iv < ei);
                                bool cp = (lane != 0) && ((dv < pud) || (dv == pud && iv < pui));
                                ed = cs ? (cp ? pud : dv) : ed;
                                ei = cs ? (cp ? pui : iv) : ei;
                                tau_d = __shfl(ed, 15);
                                tau_i = __shfl(ei, 15);
                            }
                        }
                    }
                    __syncthreads();
                }
                if (lane < K_) {
                    int v = ei;
                    v = ((unsigned)v < (unsigned)N_) ? v : 0;          // fault guard
                    knn[(size_t)row * K_ + lane] = v;
                }
                // BN stats + k-max over the SAME loads. lane L owns o = L+64j.
                float mx[4] = {-INFINITY, -INFINITY, -INFINITY, -INFINITY};
#pragma unroll
                for (int k = 0; k < K_; ++k) {
                    int iv = __shfl(ei, k);
                    iv = ((unsigned)iv < (unsigned)N_) ? iv : 0;       // fault guard
                    const float* hrow = hp + ((size_t)b * N_ + iv) * COUT_;
#pragma unroll
                    for (int j = 0; j < 4; ++j) {
                        float hv = hrow[lane + 64 * j];
                        double h = (double)hv;
                        sAcc[j] += h;
                        s2Acc[j] += h * h;
                        mx[j] = fmaxf(mx[j], hv);
                    }
                }
                // store k-max at its FINAL transposed y address (hidden scatter)
#pragma unroll
                for (int j = 0; j < 4; ++j)
                    ymax[((size_t)b * COUT_ + (lane + 64 * j)) * M_ + m] = mx[j];
            }

            // per-wave partials -> LDS, cross-wave reduce, block partial out
            double (*wacc)[512] = sm.k.wacc;
#pragma unroll
            for (int j = 0; j < 4; ++j) {
                wacc[w][lane + 64 * j] = sAcc[j];
                wacc[w][256 + lane + 64 * j] = s2Acc[j];
            }
            __syncthreads();
            double tsum = 0.0;
#pragma unroll
            for (int wv = 0; wv < 8; ++wv) tsum += wacc[wv][tid];
            partial[(size_t)wkr * 512 + tid] = tsum;
        }

        // ==== worker barrier #2 arrive; block 0 computes scale/bias ========
        __threadfence();
        if (tid == 0)
            __hip_atomic_fetch_add(&gbar[1], 1, __ATOMIC_RELEASE, __HIP_MEMORY_SCOPE_AGENT);
        if (wkr == 0) {
            if (tid == 0) {
                while (__hip_atomic_load(&gbar[1], __ATOMIC_ACQUIRE, __HIP_MEMORY_SCOPE_AGENT) < WORKERS)
                    __builtin_amdgcn_s_sleep(8);
            }
            __syncthreads();
            if (tid < 256) {
                int o = tid;
                double s = 0.0, s2 = 0.0;
                for (int j = 0; j < WORKERS; ++j) {          // IDENTICAL order to old bn_final
                    s += partial[(size_t)j * 512 + o];
                    s2 += partial[(size_t)j * 512 + 256 + o];
                }
                const double inv = 1.0 / (double)(B_ * M_ * K_);
                double mean = s * inv;
                double var = s2 * inv - mean * mean;
                if (var < 0.0) var = 0.0;
                double r = 1.0 / sqrt(var + 1e-5);
                double gm = (double)gamma[o];
                scale[o] = (float)(r * gm);
                bias[o] = (float)((double)beta[o] - mean * r * gm);
            }
        }
    }
}

// ---------------------------------------------------------------------------
// Finalize (R10 form): y holds mx = max_k hp. s>=0: y = relu(s*y+t) in place
// — BIT-IDENTICAL to relu(max_k(h*s+t)) by weak monotonicity of float
// mul/add with s>=0. s<0 fallback keeps general correctness.
// ---------------------------------------------------------------------------
__global__ __launch_bounds__(256) void finalize_kernel(const float* __restrict__ hp,
                                                       const int* __restrict__ knn,
                                                       const float* __restrict__ scale,
                                                       const float* __restrict__ bias,
                                                       float* __restrict__ y) {
    const int b = blockIdx.x >> 8;            // 2048 blocks: (b, o)
    const int o = blockIdx.x & 255;
    const float s = scale[o];
    const float t = bias[o];
    float* yrow = y + ((size_t)b * COUT_ + o) * M_;
    const int tid = threadIdx.x;
    if (s >= 0.0f) {
#pragma unroll
        for (int i = 0; i < 8; ++i) {
            int m = tid + 256 * i;
            float h = yrow[m];                // mx
            float v = h * s + t;              // same expression as old per-k form
            yrow[m] = fmaxf(v, 0.0f);
        }
    } else {
        for (int i = 0; i < 8; ++i) {
            int m = tid + 256 * i;
            float v = -INFINITY;
            for (int k = 0; k < K_; ++k) {
                int n = knn[(size_t)(b * M_ + m) * K_ + k];
                n = ((unsigned)n < (unsigned)N_) ? n : 0;   // fault guard
                float h = hp[((size_t)b * N_ + n) * COUT_ + o];
                v = fmaxf(v, h * s + t);
            }
            yrow[m] = fmaxf(v, 0.0f);
        }
    }
}

__global__ void sentinel_kernel(float* out, float v) { out[0] = v; }

// ---------------------------------------------------------------------------
extern "C" void kernel_launch(void* const* d_in, const int* in_sizes, int n_in,
                              void* d_out, int out_size, void* d_ws, size_t ws_size,
                              hipStream_t stream) {
    const float* x = (const float*)d_in[0];
    const float* coords = (const float*)d_in[1];
    const float* W = (const float*)d_in[2];
    const float* gamma = (const float*)d_in[3];
    const float* beta = (const float*)d_in[4];
    float* y = (float*)d_out;
    float* out_fps = y + (size_t)B_ * COUT_ * M_;     // fps_coords after y (f32)

    if (n_in != 5 ||
        in_sizes[0] != B_ * CIN_ * N_ ||
        in_sizes[1] != B_ * 3 * N_ ||
        in_sizes[2] != COUT_ * CIN_ ||
        in_sizes[3] != COUT_ || in_sizes[4] != COUT_ ||
        out_size != B_ * COUT_ * M_ + B_ * 3 * M_) {
        sentinel_kernel<<<1, 1, 0, stream>>>(y, -2.0e6f);
        return;
    }

    const size_t HP_BYTES = (size_t)B_ * N_ * COUT_ * 4;          // 64 MB
    const size_t KNN_BYTES = (size_t)B_ * M_ * K_ * 4;            // 1 MB
    const size_t PART_BYTES = (size_t)WORKERS * 512 * 8;          // 983 KB
    const size_t WFLAG_BYTES = (size_t)B_ * M_ * FSTRIDE * 4;     // 1 MB (padded)
    const size_t NEED = HP_BYTES + KNN_BYTES + PART_BYTES + WFLAG_BYTES + 8192;
    if (ws_size < NEED) {
        sentinel_kernel<<<1, 1, 0, stream>>>(y, -1.0e6f);
        return;
    }
    char* ws = (char*)d_ws;
    float* hp = (float*)ws;
    int* knn = (int*)(ws + HP_BYTES);
    double* partial = (double*)(ws + HP_BYTES + KNN_BYTES);
    unsigned* wflag = (unsigned*)(ws + HP_BYTES + KNN_BYTES + PART_BYTES);
    char* tail = ws + HP_BYTES + KNN_BYTES + PART_BYTES + WFLAG_BYTES;
    int* gbar = (int*)tail;                                        // 2 counters
    float* scale = (float*)(tail + 256);
    float* bias = scale + 256;

    (void)hipMemsetAsync(wflag, 0xFF, WFLAG_BYTES, stream);        // winner flags = empty
    (void)hipMemsetAsync(gbar, 0, 256, stream);                    // barriers = 0

    mega_kernel<<<B_ + WORKERS, 512, 0, stream>>>(coords, x, W, wflag, out_fps,
                                                  hp, knn, partial, gbar, y,
                                                  gamma, beta, scale, bias);
    finalize_kernel<<<B_ * COUT_, 256, 0, stream>>>(hp, knn, scale, bias, y);
}